// Round 3
// baseline (2729.808 us; speedup 1.0000x reference)
//
#include <hip/hip_runtime.h>

typedef unsigned short u16;
typedef __attribute__((ext_vector_type(8))) __bf16 bf16x8;
typedef __attribute__((ext_vector_type(4))) float f32x4;

#define DT_STEP 0.01f

// ---- workspace layout (bytes) ----
// All matrix operands live in "MFMA-staged layout": element (row, kk) of a
// [rows x K] K-major matrix is stored in 1KB blocks of 16 rows x 32 kk:
//   off_u16 = ((row>>4)*KB + (kk>>5))*512 + (((kk>>3)&3)*16 + (row&15))*8 + (kk&7)
// so a wave's MFMA fragment load is exactly 16B per lane at base + lane*16B.
//
// Wall : 3968 rows x 512 K (KB=16)  : row k*496+i = sqrt(r_k)*L_k[i,:]
// Aop2 : 496 rows x 5632 K (KB=176) : KB 0..127 = SwC (setup) then Tflat (steps)
//                                     KB 128..143 = -0.5*G
//                                     KB 144..159 = -0.5*rho slot0
//                                     KB 160..175 = -0.5*rho slot1
// Bop2 : 496 rows x 5632 K (KB=176) : KB 0..127 = SwT (sqrt(r_k)*L_k blocks)
//                                     KB 128..143 = G
//                                     KB 144..159 = rho slot0
//                                     KB 160..175 = rho slot1
// accum: 496*496 f32 split-K accumulator (re-zeroed by finalizer)
// cnt  : 64 int per-C-tile arrival counters
static const size_t OFF_WALL = 0;
static const size_t OFF_AOP2 = 4063232;    // 248*16*512*2
static const size_t OFF_BOP2 = 9650176;    // + 31*176*512*2
static const size_t OFF_ACC  = 15237120;   // + 31*176*512*2
static const size_t OFF_CNT  = 16221184;   // + 496*496*4
static const size_t WS_NEED  = 16221440;

static __device__ __forceinline__ u16 f2bf(float x){
  unsigned u = __float_as_uint(x);
  u = u + 0x7FFFu + ((u >> 16) & 1u);   // RNE
  return (u16)(u >> 16);
}

static __device__ __forceinline__ size_t stx(int row, int kk, int KB){
  return ((size_t)((row >> 4) * KB + (kk >> 5)) << 9)
       + (size_t)(((((kk >> 3) & 3) * 16) + (row & 15)) << 3) + (kk & 7);
}

// K0a: fill Wall (staged) and SwT region of Bop2 (staged). K-pads -> 0.
__global__ __launch_bounds__(256) void k0a(const float* __restrict__ L,
                                           const float* __restrict__ rates,
                                           u16* __restrict__ Wall,
                                           u16* __restrict__ Bop2){
  int id = blockIdx.x * 256 + threadIdx.x;
  if (id >= 8*496*512) return;
  int k   = id / (496*512);
  int rem = id - k*(496*512);
  int i   = rem >> 9;
  int j   = rem & 511;
  float rt = sqrtf(fabsf(rates[k]));
  float v = 0.0f;
  if (j < 496) v = rt * L[(size_t)k*246016 + i*496 + j];
  u16 h = f2bf(v);
  Wall[stx(k*496 + i, j, 16)] = h;
  Bop2[stx(i, (k << 9) + j, 176)] = h;
}

// K0b: SwC[i, k*512+j] = sqrt(r_k)*L_k[j,i] into Aop2 KB 0..127 (LDS transpose).
__global__ __launch_bounds__(256) void k0b(const float* __restrict__ L,
                                           const float* __restrict__ rates,
                                           u16* __restrict__ Aop2){
  __shared__ float tile[32][33];
  int k  = blockIdx.z;
  int i0 = blockIdx.x * 32;
  int j0 = blockIdx.y * 32;
  int tx = threadIdx.x, ty = threadIdx.y;  // 32 x 8
  float rt = sqrtf(fabsf(rates[k]));
  #pragma unroll
  for (int p = 0; p < 4; ++p){
    int j = j0 + ty + p*8;   // row of L_k
    int i = i0 + tx;         // col of L_k
    float v = 0.0f;
    if (j < 496 && i < 496) v = rt * L[(size_t)k*246016 + j*496 + i];
    tile[ty + p*8][tx] = v;
  }
  __syncthreads();
  #pragma unroll
  for (int p = 0; p < 4; ++p){
    int i = i0 + ty + p*8;   // SwC row
    int j = j0 + tx;         // col within k-block (pads get 0 via load guard)
    if (i < 496) Aop2[stx(i, (k << 9) + j, 176)] = f2bf(tile[tx][ty + p*8]);
  }
}

// K0c: rho into slot0 (staged), zero slot1 + G pads, d_out=rho0, accum/cnt zero.
__global__ __launch_bounds__(256) void k0c(const float* __restrict__ rho0,
                                           u16* __restrict__ Aop2,
                                           u16* __restrict__ Bop2,
                                           float* __restrict__ dout,
                                           float* __restrict__ accum,
                                           int* __restrict__ cnt){
  int id = blockIdx.x * 256 + threadIdx.x;
  if (id >= 496*512) return;
  int i = id >> 9, j = id & 511;
  float f = (j < 496) ? rho0[(size_t)i*496 + j] : 0.0f;
  Bop2[stx(i, 4608 + j, 176)] = f2bf(f);
  Aop2[stx(i, 4608 + j, 176)] = f2bf(-0.5f*f);
  Bop2[stx(i, 5120 + j, 176)] = 0;
  Aop2[stx(i, 5120 + j, 176)] = 0;
  if (j >= 496){ Bop2[stx(i, 4096 + j, 176)] = 0; Aop2[stx(i, 4096 + j, 176)] = 0; }
  if (j < 496){ dout[(size_t)i*496 + j] = f; accum[(size_t)i*496 + j] = 0.0f; }
  if (id < 64) cnt[id] = 0;
}

// Direct-to-register NT GEMM on staged operands with an EXPLICIT rotated
// register pipeline (DEPTH slots, statically indexed -> compiler must keep
// DEPTH*4 b128 loads in flight with fine-grained vmcnt waits).
// MODE 0: phase A, T_k = L~_k * rho. grid (62, 8). NKT=16, DEPTH=4.
// MODE 1: G = SwC * SwC^T (setup, once). grid (8, 8). NKT=128, DEPTH=4.
// MODE 2: phase B, K=5120 logical, SYMMETRIC output: grid (16 splits, 36
//         lower-tri tile pairs). Split-K on blockIdx.x (fastest dim ->
//         round-robin XCDs -> each XCD's K-slice stays L2-resident).
//         Last arrival finalizes tile AND its mirror.
template<int MODE>
__global__ __launch_bounds__(256) void gemm_nt(
    const u16* __restrict__ Ast, const u16* __restrict__ Bst,
    int rhoKB, u16* __restrict__ Aop2, u16* __restrict__ Bop2,
    float* __restrict__ accum, int* __restrict__ cnt,
    float* __restrict__ dout, int rhoKBN)
{
  __shared__ int sticket;
  const int t    = threadIdx.x;
  const int lane = t & 63;
  const int w    = t >> 6;
  const int wm   = w & 1, wn = w >> 1;

  constexpr int DEPTH = (MODE == 2) ? 5 : 4;
  constexpr int NKT   = (MODE == 0) ? 16 : (MODE == 1 ? 128 : 10);

  int tm, tn, kt0 = 0;
  if (MODE == 2){
    kt0 = blockIdx.x * 10;
    int rem = blockIdx.y, tmv = 0;
    while (rem >= 8 - tmv){ rem -= 8 - tmv; ++tmv; }
    tm = tmv; tn = tmv + rem;          // tm <= tn
  } else { tm = blockIdx.x; tn = blockIdx.y; }

  const int KBa = (MODE == 0) ? 16 : 176;
  const int KBb = 176;
  const int RA0 = tm*4 + wm*2;
  const int RB0 = tn*4 + wn*2;
  const size_t laneu = (size_t)lane * 8;
  const size_t strA = (size_t)KBa << 9;
  const size_t strB = (size_t)KBb << 9;
  const u16* baseA = Ast + (((size_t)RA0 * KBa) << 9) + laneu;
  const u16* baseB = Bst + (((size_t)RB0 * KBb) << 9) + laneu;

  auto colmap = [&](int kt, int& ka, int& kb){
    if (MODE == 0){ ka = kt; kb = rhoKB + kt; }
    else if (MODE == 1){ ka = kt; kb = kt; }
    else {
      if (kt < 128)      { ka = kt;               kb = kt; }
      else if (kt < 144) { ka = kt;               kb = rhoKB + kt - 128; }
      else               { ka = rhoKB + kt - 144; kb = kt - 16; }
    }
  };

  bf16x8 Ar[DEPTH][2], Br[DEPTH][2];
  f32x4 acc[2][2];
  #pragma unroll
  for (int a = 0; a < 2; ++a)
    #pragma unroll
    for (int b = 0; b < 2; ++b)
      acc[a][b] = (f32x4){0.f, 0.f, 0.f, 0.f};

  // prologue: fill all DEPTH slots
  #pragma unroll
  for (int p = 0; p < DEPTH; ++p){
    int ka, kb; colmap(kt0 + p, ka, kb);
    const u16* pa = baseA + ((size_t)ka << 9);
    const u16* pb = baseB + ((size_t)kb << 9);
    Ar[p][0] = *(const bf16x8*)(pa);
    Ar[p][1] = *(const bf16x8*)(pa + strA);
    Br[p][0] = *(const bf16x8*)(pb);
    Br[p][1] = *(const bf16x8*)(pb + strB);
  }

  // steady state: compute slot p, refill slot p from iter+DEPTH
  for (int it = 0; it < NKT - DEPTH; it += DEPTH){
    #pragma unroll
    for (int p = 0; p < DEPTH; ++p){
      acc[0][0] = __builtin_amdgcn_mfma_f32_16x16x32_bf16(Ar[p][0], Br[p][0], acc[0][0], 0, 0, 0);
      acc[0][1] = __builtin_amdgcn_mfma_f32_16x16x32_bf16(Ar[p][0], Br[p][1], acc[0][1], 0, 0, 0);
      acc[1][0] = __builtin_amdgcn_mfma_f32_16x16x32_bf16(Ar[p][1], Br[p][0], acc[1][0], 0, 0, 0);
      acc[1][1] = __builtin_amdgcn_mfma_f32_16x16x32_bf16(Ar[p][1], Br[p][1], acc[1][1], 0, 0, 0);
      int ka, kb; colmap(kt0 + it + p + DEPTH, ka, kb);
      const u16* pa = baseA + ((size_t)ka << 9);
      const u16* pb = baseB + ((size_t)kb << 9);
      Ar[p][0] = *(const bf16x8*)(pa);
      Ar[p][1] = *(const bf16x8*)(pa + strA);
      Br[p][0] = *(const bf16x8*)(pb);
      Br[p][1] = *(const bf16x8*)(pb + strB);
    }
  }
  // epilogue: drain remaining DEPTH slots
  #pragma unroll
  for (int p = 0; p < DEPTH; ++p){
    acc[0][0] = __builtin_amdgcn_mfma_f32_16x16x32_bf16(Ar[p][0], Br[p][0], acc[0][0], 0, 0, 0);
    acc[0][1] = __builtin_amdgcn_mfma_f32_16x16x32_bf16(Ar[p][0], Br[p][1], acc[0][1], 0, 0, 0);
    acc[1][0] = __builtin_amdgcn_mfma_f32_16x16x32_bf16(Ar[p][1], Br[p][0], acc[1][0], 0, 0, 0);
    acc[1][1] = __builtin_amdgcn_mfma_f32_16x16x32_bf16(Ar[p][1], Br[p][1], acc[1][1], 0, 0, 0);
  }

  const int quad = lane >> 4, c16 = lane & 15;
  #pragma unroll
  for (int mi = 0; mi < 2; ++mi)
  #pragma unroll
  for (int ni = 0; ni < 2; ++ni)
  #pragma unroll
  for (int r = 0; r < 4; ++r){
    int row = tm*64 + wm*32 + mi*16 + quad*4 + r;
    int col = tn*64 + wn*32 + ni*16 + c16;
    float v = acc[mi][ni][r];
    if (MODE == 0){
      int k  = row / 496;
      int i2 = row - k*496;
      Aop2[stx(i2, (k << 9) + col, 176)] = f2bf(v);   // pads benign (SwT pads are 0)
    } else if (MODE == 1){
      if (row < 496 && col < 496){
        Bop2[stx(row, 4096 + col, 176)] = f2bf(v);
        Aop2[stx(row, 4096 + col, 176)] = f2bf(-0.5f*v);
      }
    } else {
      if (row < 496 && col < 496)
        atomicAdd(&accum[row*496 + col], v);
    }
  }

  if (MODE == 2){
    __threadfence();                               // release our partial adds
    if (t == 0) sticket = atomicAdd(&cnt[tm*8 + tn], 1);
    __syncthreads();
    if (sticket == 15){                            // last of 16 split-K blocks
      __threadfence();                             // acquire
      #pragma unroll
      for (int mi = 0; mi < 2; ++mi)
      #pragma unroll
      for (int ni = 0; ni < 2; ++ni)
      #pragma unroll
      for (int r = 0; r < 4; ++r){
        int row = tm*64 + wm*32 + mi*16 + quad*4 + r;
        int col = tn*64 + wn*32 + ni*16 + c16;
        if (row < 496 && col < 496){
          int e = row*496 + col;
          float tot = __hip_atomic_load(&accum[e], __ATOMIC_RELAXED, __HIP_MEMORY_SCOPE_AGENT);
          float rnew = dout[e] + DT_STEP * tot;
          u16 hb = f2bf(rnew), ha = f2bf(-0.5f*rnew);
          dout[e] = rnew;                          // fp32 state lives in d_out
          Bop2[stx(row, (rhoKBN << 5) + col, 176)] = hb;
          Aop2[stx(row, (rhoKBN << 5) + col, 176)] = ha;
          accum[e] = 0.0f;                         // ready for next step
          if (tm != tn){                           // mirror into upper tile
            dout[col*496 + row] = rnew;
            Bop2[stx(col, (rhoKBN << 5) + row, 176)] = hb;
            Aop2[stx(col, (rhoKBN << 5) + row, 176)] = ha;
          }
        }
      }
      if (t == 0) cnt[tm*8 + tn] = 0;
    }
  }
}

extern "C" void kernel_launch(void* const* d_in, const int* in_sizes, int n_in,
                              void* d_out, int out_size, void* d_ws, size_t ws_size,
                              hipStream_t stream)
{
  (void)in_sizes; (void)n_in; (void)out_size;
  if (ws_size < WS_NEED) return;
  const float* rho0  = (const float*)d_in[0];
  // d_in[1] (H_real) provably does not affect the real forward output.
  const float* L     = (const float*)d_in[2];
  const float* rates = (const float*)d_in[3];
  float* dout = (float*)d_out;
  char* ws = (char*)d_ws;
  u16* Wall    = (u16*)(ws + OFF_WALL);
  u16* Aop2    = (u16*)(ws + OFF_AOP2);
  u16* Bop2    = (u16*)(ws + OFF_BOP2);
  float* accum = (float*)(ws + OFF_ACC);
  int* cnt     = (int*)(ws + OFF_CNT);

  k0a<<<dim3((8*496*512 + 255)/256), dim3(256), 0, stream>>>(L, rates, Wall, Bop2);
  k0b<<<dim3(16,16,8), dim3(32,8), 0, stream>>>(L, rates, Aop2);
  k0c<<<dim3((496*512 + 255)/256), dim3(256), 0, stream>>>(rho0, Aop2, Bop2, dout, accum, cnt);
  // G = sum_k r_k L_k^T L_k  (once)
  gemm_nt<1><<<dim3(8,8), dim3(256), 0, stream>>>(
      Aop2, Aop2, 0, Aop2, Bop2, accum, cnt, dout, 0);

  for (int s = 0; s < 32; ++s){
    int rhoKB  = 144 + 16*(s & 1);
    int rhoKBN = 144 + 16*((s+1) & 1);
    // phase A: T_k = sqrt(r_k) L_k * rho  (rho symmetric -> row-major rho is B^T)
    gemm_nt<0><<<dim3(62,8), dim3(256), 0, stream>>>(
        Wall, Bop2, rhoKB, Aop2, Bop2, accum, cnt, dout, 0);
    // phase B: rho += DT*( sum_k T_k L~_k^T - 0.5(G rho + rho G) ), symmetric
    gemm_nt<2><<<dim3(16,36), dim3(256), 0, stream>>>(
        Aop2, Bop2, rhoKB, Aop2, Bop2, accum, cnt, dout, rhoKBN);
  }
}

// Round 4
// 856.640 us; speedup vs baseline: 3.1866x; 3.1866x over previous
//
#include <hip/hip_runtime.h>

typedef unsigned short u16;
typedef __attribute__((ext_vector_type(8))) __bf16 bf16x8;
typedef __attribute__((ext_vector_type(4))) float f32x4;

#define DT_STEP 0.01f

// ---- workspace layout (bytes) ----
// All matrix operands live in "MFMA-staged layout": element (row, kk) of a
// [rows x K] K-major matrix is stored in 1KB blocks of 16 rows x 32 kk:
//   off_u16 = ((row>>4)*KB + (kk>>5))*512 + (((kk>>3)&3)*16 + (row&15))*8 + (kk&7)
// so a wave's MFMA fragment load is exactly 16B per lane at base + lane*16B.
//
// Wall : 3968 rows x 512 K (KB=16)  : row k*496+i = sqrt(r_k)*L_k[i,:]
// Aop2 : 496 rows x 5632 K (KB=176) : KB 0..127 = SwC (setup) then Tflat (steps)
//                                     KB 128..143 = -0.5*G
//                                     KB 144..159 = -0.5*rho slot0
//                                     KB 160..175 = -0.5*rho slot1
// Bop2 : 496 rows x 5632 K (KB=176) : KB 0..127 = SwT (sqrt(r_k)*L_k blocks)
//                                     KB 128..143 = G
//                                     KB 144..159 = rho slot0
//                                     KB 160..175 = rho slot1
// pad  : former accum region, kept mapped so benign OOB reads of row-block 31
//        (rows 496..511, results discarded) stay in-bounds.
static const size_t OFF_WALL = 0;
static const size_t OFF_AOP2 = 4063232;    // 248*16*512*2
static const size_t OFF_BOP2 = 9650176;    // + 31*176*512*2
static const size_t OFF_PAD  = 15237120;   // + 31*176*512*2
static const size_t WS_NEED  = 16221440;

static __device__ __forceinline__ u16 f2bf(float x){
  unsigned u = __float_as_uint(x);
  u = u + 0x7FFFu + ((u >> 16) & 1u);   // RNE
  return (u16)(u >> 16);
}

static __device__ __forceinline__ size_t stx(int row, int kk, int KB){
  return ((size_t)((row >> 4) * KB + (kk >> 5)) << 9)
       + (size_t)(((((kk >> 3) & 3) * 16) + (row & 15)) << 3) + (kk & 7);
}

// K0a: fill Wall (staged) and SwT region of Bop2 (staged). K-pads -> 0.
__global__ __launch_bounds__(256) void k0a(const float* __restrict__ L,
                                           const float* __restrict__ rates,
                                           u16* __restrict__ Wall,
                                           u16* __restrict__ Bop2){
  int id = blockIdx.x * 256 + threadIdx.x;
  if (id >= 8*496*512) return;
  int k   = id / (496*512);
  int rem = id - k*(496*512);
  int i   = rem >> 9;
  int j   = rem & 511;
  float rt = sqrtf(fabsf(rates[k]));
  float v = 0.0f;
  if (j < 496) v = rt * L[(size_t)k*246016 + i*496 + j];
  u16 h = f2bf(v);
  Wall[stx(k*496 + i, j, 16)] = h;
  Bop2[stx(i, (k << 9) + j, 176)] = h;
}

// K0b: SwC[i, k*512+j] = sqrt(r_k)*L_k[j,i] into Aop2 KB 0..127 (LDS transpose).
__global__ __launch_bounds__(256) void k0b(const float* __restrict__ L,
                                           const float* __restrict__ rates,
                                           u16* __restrict__ Aop2){
  __shared__ float tile[32][33];
  int k  = blockIdx.z;
  int i0 = blockIdx.x * 32;
  int j0 = blockIdx.y * 32;
  int tx = threadIdx.x, ty = threadIdx.y;  // 32 x 8
  float rt = sqrtf(fabsf(rates[k]));
  #pragma unroll
  for (int p = 0; p < 4; ++p){
    int j = j0 + ty + p*8;   // row of L_k
    int i = i0 + tx;         // col of L_k
    float v = 0.0f;
    if (j < 496 && i < 496) v = rt * L[(size_t)k*246016 + j*496 + i];
    tile[ty + p*8][tx] = v;
  }
  __syncthreads();
  #pragma unroll
  for (int p = 0; p < 4; ++p){
    int i = i0 + ty + p*8;   // SwC row
    int j = j0 + tx;         // col within k-block (pads get 0 via load guard)
    if (i < 496) Aop2[stx(i, (k << 9) + j, 176)] = f2bf(tile[tx][ty + p*8]);
  }
}

// K0c: rho into slot0 (staged), zero slot1 + G pads, d_out = rho0.
__global__ __launch_bounds__(256) void k0c(const float* __restrict__ rho0,
                                           u16* __restrict__ Aop2,
                                           u16* __restrict__ Bop2,
                                           float* __restrict__ dout){
  int id = blockIdx.x * 256 + threadIdx.x;
  if (id >= 496*512) return;
  int i = id >> 9, j = id & 511;
  float f = (j < 496) ? rho0[(size_t)i*496 + j] : 0.0f;
  Bop2[stx(i, 4608 + j, 176)] = f2bf(f);
  Aop2[stx(i, 4608 + j, 176)] = f2bf(-0.5f*f);
  Bop2[stx(i, 5120 + j, 176)] = 0;
  Aop2[stx(i, 5120 + j, 176)] = 0;
  if (j >= 496){ Bop2[stx(i, 4096 + j, 176)] = 0; Aop2[stx(i, 4096 + j, 176)] = 0; }
  if (j < 496) dout[(size_t)i*496 + j] = f;
}

// Direct-to-register NT GEMM on staged operands, rotated register pipeline.
// MODE 0: phase A, T_k = L~_k * rho. grid (62, 8), NKT=16, DEPTH=4.
//         Epilogue -> staged Tflat (pad cols written as 0 -> no NaN hazard).
// MODE 1: G = SwC * SwC^T (setup, once). grid (8, 8), NKT=128, DEPTH=4.
template<int MODE>
__global__ __launch_bounds__(256, 2) void gemm_nt(
    const u16* __restrict__ Ast, const u16* __restrict__ Bst,
    int rhoKB, u16* Aop2, u16* Bop2)
{
  const int t    = threadIdx.x;
  const int lane = t & 63;
  const int w    = t >> 6;
  const int wm   = w & 1, wn = w >> 1;
  const int tm   = blockIdx.x, tn = blockIdx.y;

  constexpr int DEPTH = 4;
  constexpr int NKT   = (MODE == 0) ? 16 : 128;
  const int KBa = (MODE == 0) ? 16 : 176;
  const int KBb = 176;
  const int RA0 = tm*4 + wm*2;
  const int RB0 = tn*4 + wn*2;
  const size_t laneu = (size_t)lane * 8;
  const size_t strA = (size_t)KBa << 9;
  const size_t strB = (size_t)KBb << 9;
  const u16* baseA = Ast + (((size_t)RA0 * KBa) << 9) + laneu;
  const u16* baseB = Bst + (((size_t)RB0 * KBb) << 9) + laneu;

  auto colmap = [&](int kt, int& ka, int& kb){
    if (MODE == 0){ ka = kt; kb = rhoKB + kt; }
    else          { ka = kt; kb = kt; }
  };

  bf16x8 Ar[DEPTH][2], Br[DEPTH][2];
  f32x4 acc[2][2];
  #pragma unroll
  for (int a = 0; a < 2; ++a)
    #pragma unroll
    for (int b = 0; b < 2; ++b)
      acc[a][b] = (f32x4){0.f, 0.f, 0.f, 0.f};

  #pragma unroll
  for (int p = 0; p < DEPTH; ++p){
    int ka, kb; colmap(p, ka, kb);
    const u16* pa = baseA + ((size_t)ka << 9);
    const u16* pb = baseB + ((size_t)kb << 9);
    Ar[p][0] = *(const bf16x8*)(pa);
    Ar[p][1] = *(const bf16x8*)(pa + strA);
    Br[p][0] = *(const bf16x8*)(pb);
    Br[p][1] = *(const bf16x8*)(pb + strB);
  }
  for (int it = 0; it < NKT - DEPTH; it += DEPTH){
    #pragma unroll
    for (int p = 0; p < DEPTH; ++p){
      acc[0][0] = __builtin_amdgcn_mfma_f32_16x16x32_bf16(Ar[p][0], Br[p][0], acc[0][0], 0, 0, 0);
      acc[0][1] = __builtin_amdgcn_mfma_f32_16x16x32_bf16(Ar[p][0], Br[p][1], acc[0][1], 0, 0, 0);
      acc[1][0] = __builtin_amdgcn_mfma_f32_16x16x32_bf16(Ar[p][1], Br[p][0], acc[1][0], 0, 0, 0);
      acc[1][1] = __builtin_amdgcn_mfma_f32_16x16x32_bf16(Ar[p][1], Br[p][1], acc[1][1], 0, 0, 0);
      int ka, kb; colmap(it + p + DEPTH, ka, kb);
      const u16* pa = baseA + ((size_t)ka << 9);
      const u16* pb = baseB + ((size_t)kb << 9);
      Ar[p][0] = *(const bf16x8*)(pa);
      Ar[p][1] = *(const bf16x8*)(pa + strA);
      Br[p][0] = *(const bf16x8*)(pb);
      Br[p][1] = *(const bf16x8*)(pb + strB);
    }
  }
  #pragma unroll
  for (int p = 0; p < DEPTH; ++p){
    acc[0][0] = __builtin_amdgcn_mfma_f32_16x16x32_bf16(Ar[p][0], Br[p][0], acc[0][0], 0, 0, 0);
    acc[0][1] = __builtin_amdgcn_mfma_f32_16x16x32_bf16(Ar[p][0], Br[p][1], acc[0][1], 0, 0, 0);
    acc[1][0] = __builtin_amdgcn_mfma_f32_16x16x32_bf16(Ar[p][1], Br[p][0], acc[1][0], 0, 0, 0);
    acc[1][1] = __builtin_amdgcn_mfma_f32_16x16x32_bf16(Ar[p][1], Br[p][1], acc[1][1], 0, 0, 0);
  }

  const int quad = lane >> 4, c16 = lane & 15;
  #pragma unroll
  for (int mi = 0; mi < 2; ++mi)
  #pragma unroll
  for (int ni = 0; ni < 2; ++ni)
  #pragma unroll
  for (int r = 0; r < 4; ++r){
    int row = tm*64 + wm*32 + mi*16 + quad*4 + r;
    int col = tn*64 + wn*32 + ni*16 + c16;
    float v = acc[mi][ni][r];
    if (MODE == 0){
      int k  = row / 496;
      int i2 = row - k*496;
      u16 hv = (col < 496) ? f2bf(v) : (u16)0;   // zero pads: no NaN into Tflat
      Aop2[stx(i2, (k << 9) + col, 176)] = hv;
    } else {
      if (row < 496 && col < 496){
        Bop2[stx(row, 4096 + col, 176)] = f2bf(v);
        Aop2[stx(row, 4096 + col, 176)] = f2bf(-0.5f*v);
      }
    }
  }
}

// Phase B: rho += DT*( sum_k T_k L~_k^T - 0.5(G rho + rho G) ), symmetric C.
// Grid = 136 blocks = lower-tri pairs of 32x32 C-tiles. Each block does full
// K=5120 with IN-BLOCK split-K across its 4 waves (1280 each, DEPTH=5 rotated
// register pipeline), LDS-reduces the 4 partials, finalizes inline (fp32 rho
// in d_out + staged bf16 rho, + mirror tile). No global atomics, no tickets.
__global__ __launch_bounds__(256, 1) void phaseB(
    const u16* __restrict__ Ac, const u16* __restrict__ Bc,
    u16* Aop2, u16* Bop2, float* dout, int rhoKB, int rhoKBN)
{
  __shared__ float red[4][32][33];
  const int t = threadIdx.x, lane = t & 63, w = t >> 6;
  int b = blockIdx.x, tm = 0;
  while (b >= 16 - tm){ b -= 16 - tm; ++tm; }
  const int tn = tm + b;                     // tm <= tn

  const int kt0 = w * 40;                    // per-wave K slice (40 kt of 32)
  const size_t laneu = (size_t)lane * 8;
  const size_t str = (size_t)176 << 9;
  const u16* baseA = Ac + (((size_t)(tm*2) * 176) << 9) + laneu;
  const u16* baseB = Bc + (((size_t)(tn*2) * 176) << 9) + laneu;

  auto colmap = [&](int kt, int& ka, int& kb){
    if (kt < 128)      { ka = kt;               kb = kt; }            // T x SwT
    else if (kt < 144) { ka = kt;               kb = rhoKB + kt-128; } // -G/2 x rho
    else               { ka = rhoKB + kt - 144; kb = kt - 16; }        // -rho/2 x G
  };

  constexpr int DEPTH = 5;
  bf16x8 Ar[DEPTH][2], Br[DEPTH][2];
  f32x4 acc[2][2];
  #pragma unroll
  for (int a = 0; a < 2; ++a)
    #pragma unroll
    for (int c = 0; c < 2; ++c)
      acc[a][c] = (f32x4){0.f, 0.f, 0.f, 0.f};

  #pragma unroll
  for (int p = 0; p < DEPTH; ++p){
    int ka, kb; colmap(kt0 + p, ka, kb);
    const u16* pa = baseA + ((size_t)ka << 9);
    const u16* pb = baseB + ((size_t)kb << 9);
    Ar[p][0] = *(const bf16x8*)(pa);
    Ar[p][1] = *(const bf16x8*)(pa + str);
    Br[p][0] = *(const bf16x8*)(pb);
    Br[p][1] = *(const bf16x8*)(pb + str);
  }
  for (int it = 0; it < 40 - DEPTH; it += DEPTH){
    #pragma unroll
    for (int p = 0; p < DEPTH; ++p){
      acc[0][0] = __builtin_amdgcn_mfma_f32_16x16x32_bf16(Ar[p][0], Br[p][0], acc[0][0], 0, 0, 0);
      acc[0][1] = __builtin_amdgcn_mfma_f32_16x16x32_bf16(Ar[p][0], Br[p][1], acc[0][1], 0, 0, 0);
      acc[1][0] = __builtin_amdgcn_mfma_f32_16x16x32_bf16(Ar[p][1], Br[p][0], acc[1][0], 0, 0, 0);
      acc[1][1] = __builtin_amdgcn_mfma_f32_16x16x32_bf16(Ar[p][1], Br[p][1], acc[1][1], 0, 0, 0);
      int ka, kb; colmap(kt0 + it + p + DEPTH, ka, kb);
      const u16* pa = baseA + ((size_t)ka << 9);
      const u16* pb = baseB + ((size_t)kb << 9);
      Ar[p][0] = *(const bf16x8*)(pa);
      Ar[p][1] = *(const bf16x8*)(pa + str);
      Br[p][0] = *(const bf16x8*)(pb);
      Br[p][1] = *(const bf16x8*)(pb + str);
    }
  }
  #pragma unroll
  for (int p = 0; p < DEPTH; ++p){
    acc[0][0] = __builtin_amdgcn_mfma_f32_16x16x32_bf16(Ar[p][0], Br[p][0], acc[0][0], 0, 0, 0);
    acc[0][1] = __builtin_amdgcn_mfma_f32_16x16x32_bf16(Ar[p][0], Br[p][1], acc[0][1], 0, 0, 0);
    acc[1][0] = __builtin_amdgcn_mfma_f32_16x16x32_bf16(Ar[p][1], Br[p][0], acc[1][0], 0, 0, 0);
    acc[1][1] = __builtin_amdgcn_mfma_f32_16x16x32_bf16(Ar[p][1], Br[p][1], acc[1][1], 0, 0, 0);
  }

  const int quad = lane >> 4, c16 = lane & 15;
  #pragma unroll
  for (int mi = 0; mi < 2; ++mi)
  #pragma unroll
  for (int ni = 0; ni < 2; ++ni)
  #pragma unroll
  for (int r = 0; r < 4; ++r)
    red[w][mi*16 + quad*4 + r][ni*16 + c16] = acc[mi][ni][r];
  __syncthreads();

  #pragma unroll
  for (int c = t; c < 1024; c += 256){
    int lr = c >> 5, lc = c & 31;
    float sum = red[0][lr][lc] + red[1][lr][lc] + red[2][lr][lc] + red[3][lr][lc];
    int row = tm*32 + lr, col = tn*32 + lc;
    if (row < 496 && col < 496){
      int e = row*496 + col;
      float rnew = dout[e] + DT_STEP * sum;
      u16 hb = f2bf(rnew), ha = f2bf(-0.5f*rnew);
      dout[e] = rnew;
      Bop2[stx(row, (rhoKBN << 5) + col, 176)] = hb;
      Aop2[stx(row, (rhoKBN << 5) + col, 176)] = ha;
      if (tm != tn){
        dout[col*496 + row] = rnew;
        Bop2[stx(col, (rhoKBN << 5) + row, 176)] = hb;
        Aop2[stx(col, (rhoKBN << 5) + row, 176)] = ha;
      }
    }
  }
}

extern "C" void kernel_launch(void* const* d_in, const int* in_sizes, int n_in,
                              void* d_out, int out_size, void* d_ws, size_t ws_size,
                              hipStream_t stream)
{
  (void)in_sizes; (void)n_in; (void)out_size;
  if (ws_size < WS_NEED) return;
  const float* rho0  = (const float*)d_in[0];
  // d_in[1] (H_real) provably does not affect the real forward output.
  const float* L     = (const float*)d_in[2];
  const float* rates = (const float*)d_in[3];
  float* dout = (float*)d_out;
  char* ws = (char*)d_ws;
  u16* Wall = (u16*)(ws + OFF_WALL);
  u16* Aop2 = (u16*)(ws + OFF_AOP2);
  u16* Bop2 = (u16*)(ws + OFF_BOP2);

  k0a<<<dim3((8*496*512 + 255)/256), dim3(256), 0, stream>>>(L, rates, Wall, Bop2);
  k0b<<<dim3(16,16,8), dim3(32,8), 0, stream>>>(L, rates, Aop2);
  k0c<<<dim3((496*512 + 255)/256), dim3(256), 0, stream>>>(rho0, Aop2, Bop2, dout);
  // G = sum_k r_k L_k^T L_k  (once)
  gemm_nt<1><<<dim3(8,8), dim3(256), 0, stream>>>(Aop2, Aop2, 0, Aop2, Bop2);

  for (int s = 0; s < 32; ++s){
    int rhoKB  = 144 + 16*(s & 1);
    int rhoKBN = 144 + 16*((s+1) & 1);
    // phase A: T_k = sqrt(r_k) L_k * rho  (rho symmetric -> row-major rho is B^T)
    gemm_nt<0><<<dim3(62,8), dim3(256), 0, stream>>>(Wall, Bop2, rhoKB, Aop2, Bop2);
    // phase B: symmetric update, no cross-block communication
    phaseB<<<dim3(136), dim3(256), 0, stream>>>(Aop2, Bop2, Aop2, Bop2, dout, rhoKB, rhoKBN);
  }
}